// Round 24
// baseline (1213.318 us; speedup 1.0000x reference)
//
#include <hip/hip_runtime.h>
#include <math.h>

#define BB 2
#define VV 4
#define NPTSC 65536
#define HH 256
#define WW 256
#define CCH 128

typedef __attribute__((ext_vector_type(8))) unsigned short ushort8;
typedef __attribute__((ext_vector_type(4))) unsigned short u16x4;
typedef __attribute__((ext_vector_type(8))) __bf16 bf16x8;
typedef __attribute__((ext_vector_type(4))) float floatx4;

// Static feats buffer (128 MiB); rewritten fully every launch.
__device__ unsigned short g_feats[(size_t)BB * VV * HH * WW * CCH];

__device__ __forceinline__ float b2f(unsigned short u) {
  unsigned int x = ((unsigned int)u) << 16;
  return __builtin_bit_cast(float, x);
}
__device__ __forceinline__ unsigned short f2b(float f) {
  unsigned int x = __builtin_bit_cast(unsigned int, f);
  x = x + 0x7fffu + ((x >> 16) & 1u);
  return (unsigned short)(x >> 16);
}

// ---- prep: f32 weights -> bf16 [out][in] into d_ws (434 KB) ----------------
__global__ __launch_bounds__(256) void mvct_prep(
    const float* __restrict__ vw_in, const float* __restrict__ vw1,
    const float* __restrict__ vw2, const float* __restrict__ vw_out,
    const float* __restrict__ gw_in, const float* __restrict__ gw1,
    const float* __restrict__ gw2, unsigned short* __restrict__ wbuf)
{
  int tid = blockIdx.x * 256 + threadIdx.x;
  if (tid >= 217088) return;
  float val;
  if (tid < 20480) {
    int n = tid / 160, k = tid - n * 160;
    val = (k < 137) ? vw_in[k * 128 + n] : 0.f;
  } else {
    int t = tid - 20480;
    const float* src;
    if (t < 49152) { src = vw1; }
    else if (t < 98304) { t -= 49152; src = vw2; }
    else if (t < 114688) { t -= 98304; src = vw_out; }
    else if (t < 131072) { t -= 114688; src = gw_in; }
    else if (t < 163840) { t -= 131072; src = gw1; }
    else { t -= 163840; src = gw2; }
    int i = t >> 14; int r = t & 16383; int n = r >> 7; int k = r & 127;
    val = src[i * 16384 + k * 128 + n];
  }
  wbuf[tid] = f2b(val);
}

// ---- conv 3x3 SAME, 1->128 ch, relu, channel-last bf16 into g_feats --------
__global__ __launch_bounds__(128) void mvct_conv(
    const float* __restrict__ views, const float* __restrict__ conv_w,
    const float* __restrict__ conv_b)
{
  int bv = blockIdx.x >> 8;
  int y = blockIdx.x & 255;
  int c = threadIdx.x;
  float w[9];
#pragma unroll
  for (int j = 0; j < 9; ++j) w[j] = conv_w[c * 9 + j];
  float bias = conv_b[c];

  __shared__ float rows[3][258];
  const float* img = views + (size_t)bv * HH * WW;
#pragma unroll
  for (int r = 0; r < 3; ++r) {
    int yy = y - 1 + r;
    for (int x = c; x < 258; x += 128) {
      int xx = x - 1;
      float v = 0.f;
      if (yy >= 0 && yy < HH && xx >= 0 && xx < WW) v = img[yy * WW + xx];
      rows[r][x] = v;
    }
  }
  __syncthreads();

  unsigned short* orow = g_feats + ((size_t)(bv * HH + y) * WW) * CCH + c;
  for (int x = 0; x < WW; ++x) {
    float acc = bias;
#pragma unroll
    for (int r = 0; r < 3; ++r)
#pragma unroll
      for (int d = 0; d < 3; ++d)
        acc += rows[r][x + d] * w[r * 3 + d];
    acc = fmaxf(acc, 0.f);
    orow[(size_t)x * CCH] = f2b(acc);
  }
}

// ---- wave-private view layer: one wave computes ALL 8 ftiles of its 16 rows.
// Acts/Dst/Res/Lo point at the wave's own row block => NO __syncthreads.
// A=weights [128][K] (m=feature), B=acts (n=row). KK = K/32.
// MODE 0: relu+store; MODE 1: relu+res+store; MODE 3: raw hi/lo split store.
template<int KK, int MODE>
__device__ __forceinline__ void vlayer(
    const unsigned short* Act, int lda,
    const unsigned short* __restrict__ Wt, int K,
    const float* __restrict__ bias,
    const unsigned short* Res, int ldr,
    unsigned short* Dst, int ldd,
    unsigned short* Lo, int ldl,
    int lane)
{
  const int col = lane & 15, quad = lane >> 4;
  ushort8 bfr[KK];
#pragma unroll
  for (int kk = 0; kk < KK; ++kk)
    bfr[kk] = *(const ushort8*)(Act + col * lda + kk * 32 + quad * 8);

  ushort8 wcur[KK];
#pragma unroll
  for (int kk = 0; kk < KK; ++kk)
    wcur[kk] = *(const ushort8*)(Wt + col * K + kk * 32 + quad * 8);

#pragma unroll
  for (int ft = 0; ft < 8; ++ft) {
    ushort8 wnext[KK];
    if (ft < 7) {
#pragma unroll
      for (int kk = 0; kk < KK; ++kk)
        wnext[kk] = *(const ushort8*)(Wt + ((ft + 1) * 16 + col) * K + kk * 32 + quad * 8);
    }
    floatx4 acc = {0.f, 0.f, 0.f, 0.f};
#pragma unroll
    for (int kk = 0; kk < KK; ++kk)
      acc = __builtin_amdgcn_mfma_f32_16x16x32_bf16(
          __builtin_bit_cast(bf16x8, wcur[kk]),
          __builtin_bit_cast(bf16x8, bfr[kk]), acc, 0, 0, 0);
    floatx4 bs = *(const floatx4*)(bias + ft * 16 + quad * 4);
    if constexpr (MODE == 3) {
      u16x4 oh, ol;
#pragma unroll
      for (int r = 0; r < 4; ++r) {
        float v = acc[r] + bs[r];
        unsigned short hi = f2b(v);
        oh[r] = hi;
        ol[r] = f2b(v - b2f(hi));
      }
      *(u16x4*)(Dst + col * ldd + ft * 16 + quad * 4) = oh;
      *(u16x4*)(Lo + col * ldl + ft * 16 + quad * 4) = ol;
    } else {
      u16x4 rv;
      if constexpr (MODE == 1)
        rv = *(const u16x4*)(Res + col * ldr + ft * 16 + quad * 4);
      u16x4 o;
#pragma unroll
      for (int r = 0; r < 4; ++r) {
        float v = acc[r] + bs[r];
        if constexpr (MODE == 1) v += b2f(rv[r]);
        o[r] = f2b(fmaxf(v, 0.f));
      }
      *(u16x4*)(Dst + col * ldd + ft * 16 + quad * 4) = o;
    }
#pragma unroll
    for (int kk = 0; kk < KK; ++kk) wcur[kk] = wnext[kk];
  }
}

// ---- weight register set for ftile-split global phase ----------------------
struct WReg {
  ushort8 a[2][4];
  floatx4 bs[2];
};

__device__ __forceinline__ WReg wload(const unsigned short* __restrict__ Wt,
                                      const float* __restrict__ bias,
                                      int lane, int ftBase) {
  WReg w;
  const int col = lane & 15, quad = lane >> 4;
#pragma unroll
  for (int ftl = 0; ftl < 2; ++ftl) {
    const int ft = ftBase + ftl;
#pragma unroll
    for (int kk = 0; kk < 4; ++kk)
      w.a[ftl][kk] = *(const ushort8*)(Wt + (ft * 16 + col) * 128 + kk * 32 + quad * 8);
    w.bs[ftl] = *(const floatx4*)(bias + ft * 16 + quad * 4);
  }
  return w;
}

// ---- ftile-split MFMA layer on 16 rows (global phase), with barrier --------
template<int MODE>
__device__ __forceinline__ void mlp_c(
    const unsigned short* Act, int lda, const WReg& w,
    const unsigned short* Res, int ldr,
    unsigned short* Dst, int ldd,
    int lane, int ftBase)
{
  const int col = lane & 15, quad = lane >> 4;
  ushort8 bfr[4];
#pragma unroll
  for (int kk = 0; kk < 4; ++kk)
    bfr[kk] = *(const ushort8*)(Act + col * lda + kk * 32 + quad * 8);
#pragma unroll
  for (int ftl = 0; ftl < 2; ++ftl) {
    const int ft = ftBase + ftl;
    floatx4 acc = {0.f, 0.f, 0.f, 0.f};
#pragma unroll
    for (int kk = 0; kk < 4; ++kk)
      acc = __builtin_amdgcn_mfma_f32_16x16x32_bf16(
          __builtin_bit_cast(bf16x8, w.a[ftl][kk]),
          __builtin_bit_cast(bf16x8, bfr[kk]), acc, 0, 0, 0);
    u16x4 rv;
    if constexpr (MODE == 1)
      rv = *(const u16x4*)(Res + col * ldr + ft * 16 + quad * 4);
    u16x4 o;
#pragma unroll
    for (int r = 0; r < 4; ++r) {
      float v = acc[r] + w.bs[ftl][r];
      if constexpr (MODE == 1) v += b2f(rv[r]);
      o[r] = f2b(fmaxf(v, 0.f));
    }
    *(u16x4*)(Dst + col * ldd + ft * 16 + quad * 4) = o;
  }
  __syncthreads();
}

// ---- main: wave-per-view, barrier-free view MLP ----------------------------
// 8192 blocks x 256 thr; wave w = view w; 16 points/block.
__global__ __launch_bounds__(256, 4) void mvct_main(
    const float* __restrict__ angles, const int* __restrict__ idx,
    const unsigned short* __restrict__ wbuf,
    const float* __restrict__ vb_in, const float* __restrict__ vb1,
    const float* __restrict__ vb2, const float* __restrict__ vb_out,
    const float* __restrict__ gb_in, const float* __restrict__ gb1,
    const float* __restrict__ gb2, const float* __restrict__ gw_out,
    const float* __restrict__ gb_out,
    float* __restrict__ out)
{
  __shared__ __align__(16) unsigned short X[64][168];   // acts / lo(r)
  __shared__ __align__(16) unsigned short Hb[64][136];  // acts / hi(r)
  const int tid = threadIdx.x;
  const int lane = tid & 63;
  const int wv = tid >> 6;                     // wave = view
  const int b = blockIdx.x >> 12;
  const int pts0 = (blockIdx.x & 4095) * 16;

  const unsigned short* w_in_t   = wbuf;
  const unsigned short* vw1_t    = wbuf + 20480;
  const unsigned short* vw2_t    = wbuf + 69632;
  const unsigned short* vw_out_t = wbuf + 118784;
  const unsigned short* gw_in_t  = wbuf + 135168;
  const unsigned short* gw1_t    = wbuf + 151552;
  const unsigned short* gw2_t    = wbuf + 184320;

  const float inv = 2.0f / 127.0f;
  const int col = lane & 15, quad = lane >> 4;
  const int rb = wv * 16;                      // own row base

  unsigned short* Xw = &X[rb][0];
  unsigned short* Hw = &Hb[rb][0];

  // PE into own rows, cols 128..159
  if (lane < 16) {
    int id = idx[pts0 + lane];
    int iz = (id >> 14) & 127, iy = (id >> 7) & 127, ix = id & 127;
    float x = ix * inv - 1.f, y = iy * inv - 1.f, z = iz * inv - 1.f;
    const float PI = 3.14159265358979323846f;
    float pe[9] = {z, y, x, sinf(PI * z), sinf(PI * y), sinf(PI * x),
                   cosf(PI * z), cosf(PI * y), cosf(PI * x)};
#pragma unroll
    for (int j = 0; j < 9; ++j) X[rb + lane][128 + j] = f2b(pe[j]);
    for (int j = 137; j < 160; ++j) X[rb + lane][j] = 0;
  }

  // sampling: own view only; 4 iters x (4 pts x 16 ch-groups)
  {
    const int bv = b * VV + wv;
    const float ang = angles[bv];
    const float ct = cosf(ang), st = sinf(ang);
    const int pl = lane >> 4, cg = lane & 15;
    for (int it = 0; it < 4; ++it) {
      int p = it * 4 + pl;
      int id = idx[pts0 + p];
      int iz = (id >> 14) & 127, iy = (id >> 7) & 127, ix = id & 127;
      float x = ix * inv - 1.f, y = iy * inv - 1.f, z = iz * inv - 1.f;
      float u = x * ct - y * st;
      float px = (u + 1.f) * 127.5f, py = (z + 1.f) * 127.5f;
      px = fminf(fmaxf(px, 0.f), 255.f);
      py = fminf(fmaxf(py, 0.f), 255.f);
      int x0 = min((int)px, 254), y0 = min((int)py, 254);
      float wx = px - (float)x0, wy = py - (float)y0;
      const unsigned short* bp =
          g_feats + ((size_t)((bv * HH + y0) * WW + x0)) * CCH + cg * 8;
      ushort8 q00 = *(const ushort8*)bp;
      ushort8 q01 = *(const ushort8*)(bp + CCH);
      ushort8 q10 = *(const ushort8*)(bp + WW * CCH);
      ushort8 q11 = *(const ushort8*)(bp + WW * CCH + CCH);
      float w00 = (1.f - wx) * (1.f - wy), w01 = wx * (1.f - wy);
      float w10 = (1.f - wx) * wy, w11 = wx * wy;
      ushort8 o;
#pragma unroll
      for (int j = 0; j < 8; ++j) {
        float f = w00 * b2f(q00[j]) + w01 * b2f(q01[j]) +
                  w10 * b2f(q10[j]) + w11 * b2f(q11[j]);
        o[j] = f2b(f);
      }
      *(ushort8*)&X[rb + p][cg * 8] = o;
    }
  }

  // ---- view MLP: 9 layers, wave-private, NO barriers ----
  vlayer<5, 0>(Xw, 168, w_in_t, 160, vb_in, nullptr, 0, Hw, 136,
               nullptr, 0, lane);
#pragma unroll 1
  for (int i = 0; i < 3; ++i) {
    vlayer<4, 0>(Hw, 136, vw1_t + i * 16384, 128, vb1 + i * 128,
                 nullptr, 0, Xw, 168, nullptr, 0, lane);
    vlayer<4, 1>(Xw, 168, vw2_t + i * 16384, 128, vb2 + i * 128,
                 Hw, 136, Hw, 136, nullptr, 0, lane);
  }
  // vw_out: raw r -> hi(Hb own rows) + lo(X own rows)
  vlayer<4, 3>(Hw, 136, vw_out_t, 128, vb_out, nullptr, 0,
               Hw, 136, Xw, 168, lane);
  __syncthreads();

  // ---- mean over views (f32 via hi+lo), ftile-split: wave w -> ftiles 2w,2w+1
  const int ftBase = wv * 2;
#pragma unroll
  for (int ftl = 0; ftl < 2; ++ftl) {
    const int ft = ftBase + ftl;
    float s[4] = {0.f, 0.f, 0.f, 0.f};
#pragma unroll
    for (int v = 0; v < VV; ++v) {
      u16x4 hi = *(const u16x4*)(&Hb[v * 16 + col][ft * 16 + quad * 4]);
      u16x4 lo = *(const u16x4*)(&X[v * 16 + col][ft * 16 + quad * 4]);
#pragma unroll
      for (int r = 0; r < 4; ++r) s[r] += b2f(hi[r]) + b2f(lo[r]);
    }
    u16x4 o;
#pragma unroll
    for (int r = 0; r < 4; ++r) o[r] = f2b(s[r] * 0.25f);
    *(u16x4*)(&X[col][ft * 16 + quad * 4]) = o;   // own ftile cols, rows 0..15
  }
  __syncthreads();

  // ---- global MLP on 16 rows, ftile-split with prefetch pipeline ----
  WReg wB = wload(gw_in_t, gb_in, lane, ftBase);
  WReg wA = wload(gw1_t, gb1, lane, ftBase);
  mlp_c<0>(&X[0][0], 168, wB, nullptr, 0, &Hb[0][0], 136, lane, ftBase);  // G0
  wB = wload(gw2_t, gb2, lane, ftBase);
  mlp_c<0>(&Hb[0][0], 136, wA, nullptr, 0, &X[0][0], 168, lane, ftBase);  // G1
  wA = wload(gw1_t + 16384, gb1 + 128, lane, ftBase);
  mlp_c<1>(&X[0][0], 168, wB, &Hb[0][0], 136, &Hb[0][0], 136, lane, ftBase); // G2
  wB = wload(gw2_t + 16384, gb2 + 128, lane, ftBase);
  mlp_c<0>(&Hb[0][0], 136, wA, nullptr, 0, &X[0][0], 168, lane, ftBase);  // G3
  mlp_c<1>(&X[0][0], 168, wB, &Hb[0][0], 136, &Hb[0][0], 136, lane, ftBase); // G4

  // out = h @ gw_out + gb_out; 16 points, 4 lanes/point (wave 0)
  if (tid < 64) {
    const int p = tid & 15, q4 = tid >> 4;
    float s = 0.f;
    const unsigned short* hr = &Hb[p][q4 * 32];
    const float* wo = gw_out + q4 * 32;
#pragma unroll
    for (int c = 0; c < 32; ++c)
      s += b2f(hr[c]) * wo[c];
    s += __shfl_xor(s, 16, 64);
    s += __shfl_xor(s, 32, 64);
    if (q4 == 0)
      out[(size_t)b * NPTSC + pts0 + p] = s + gb_out[0];
  }
}

extern "C" void kernel_launch(void* const* d_in, const int* in_sizes, int n_in,
                              void* d_out, int out_size, void* d_ws, size_t ws_size,
                              hipStream_t stream) {
  const float* views  = (const float*)d_in[0];
  const float* angles = (const float*)d_in[1];
  const int*   idx    = (const int*)d_in[2];
  const float* conv_w = (const float*)d_in[3];
  const float* conv_b = (const float*)d_in[4];
  const float* vw_in  = (const float*)d_in[5];
  const float* vb_in  = (const float*)d_in[6];
  const float* vw1    = (const float*)d_in[7];
  const float* vb1    = (const float*)d_in[8];
  const float* vw2    = (const float*)d_in[9];
  const float* vb2    = (const float*)d_in[10];
  const float* vw_out = (const float*)d_in[11];
  const float* vb_out = (const float*)d_in[12];
  const float* gw_in  = (const float*)d_in[13];
  const float* gb_in  = (const float*)d_in[14];
  const float* gw1    = (const float*)d_in[15];
  const float* gb1    = (const float*)d_in[16];
  const float* gw2    = (const float*)d_in[17];
  const float* gb2    = (const float*)d_in[18];
  const float* gw_out = (const float*)d_in[19];
  const float* gb_out = (const float*)d_in[20];

  unsigned short* wbuf = (unsigned short*)d_ws;  // 434 KB

  hipLaunchKernelGGL(mvct_prep, dim3(848), dim3(256), 0, stream,
                     vw_in, vw1, vw2, vw_out, gw_in, gw1, gw2, wbuf);
  hipLaunchKernelGGL(mvct_conv, dim3(BB * VV * HH), dim3(128), 0, stream,
                     views, conv_w, conv_b);
  hipLaunchKernelGGL(mvct_main, dim3(BB * (NPTSC / 16)), dim3(256), 0, stream,
                     angles, idx, wbuf, vb_in, vb1, vb2, vb_out,
                     gb_in, gb1, gb2, gw_out, gb_out,
                     (float*)d_out);
}

// Round 25
// 621.196 us; speedup vs baseline: 1.9532x; 1.9532x over previous
//
#include <hip/hip_runtime.h>
#include <math.h>

#define BB 2
#define VV 4
#define NPTSC 65536
#define HH 256
#define WW 256
#define CCH 128

typedef __attribute__((ext_vector_type(8))) unsigned short ushort8;
typedef __attribute__((ext_vector_type(4))) unsigned short u16x4;
typedef __attribute__((ext_vector_type(8))) __bf16 bf16x8;
typedef __attribute__((ext_vector_type(4))) float floatx4;

// Static feats buffer (128 MiB); rewritten fully every launch.
__device__ unsigned short g_feats[(size_t)BB * VV * HH * WW * CCH];

__device__ __forceinline__ float b2f(unsigned short u) {
  unsigned int x = ((unsigned int)u) << 16;
  return __builtin_bit_cast(float, x);
}
__device__ __forceinline__ unsigned short f2b(float f) {
  unsigned int x = __builtin_bit_cast(unsigned int, f);
  x = x + 0x7fffu + ((x >> 16) & 1u);
  return (unsigned short)(x >> 16);
}

// ---- prep: f32 weights -> bf16 [out][in] into d_ws (434 KB) ----------------
__global__ __launch_bounds__(256) void mvct_prep(
    const float* __restrict__ vw_in, const float* __restrict__ vw1,
    const float* __restrict__ vw2, const float* __restrict__ vw_out,
    const float* __restrict__ gw_in, const float* __restrict__ gw1,
    const float* __restrict__ gw2, unsigned short* __restrict__ wbuf)
{
  int tid = blockIdx.x * 256 + threadIdx.x;
  if (tid >= 217088) return;
  float val;
  if (tid < 20480) {
    int n = tid / 160, k = tid - n * 160;
    val = (k < 137) ? vw_in[k * 128 + n] : 0.f;
  } else {
    int t = tid - 20480;
    const float* src;
    if (t < 49152) { src = vw1; }
    else if (t < 98304) { t -= 49152; src = vw2; }
    else if (t < 114688) { t -= 98304; src = vw_out; }
    else if (t < 131072) { t -= 114688; src = gw_in; }
    else if (t < 163840) { t -= 131072; src = gw1; }
    else { t -= 163840; src = gw2; }
    int i = t >> 14; int r = t & 16383; int n = r >> 7; int k = r & 127;
    val = src[i * 16384 + k * 128 + n];
  }
  wbuf[tid] = f2b(val);
}

// ---- conv 3x3 SAME, 1->128 ch, relu, channel-last bf16 into g_feats --------
__global__ __launch_bounds__(128) void mvct_conv(
    const float* __restrict__ views, const float* __restrict__ conv_w,
    const float* __restrict__ conv_b)
{
  int bv = blockIdx.x >> 8;
  int y = blockIdx.x & 255;
  int c = threadIdx.x;
  float w[9];
#pragma unroll
  for (int j = 0; j < 9; ++j) w[j] = conv_w[c * 9 + j];
  float bias = conv_b[c];

  __shared__ float rows[3][258];
  const float* img = views + (size_t)bv * HH * WW;
#pragma unroll
  for (int r = 0; r < 3; ++r) {
    int yy = y - 1 + r;
    for (int x = c; x < 258; x += 128) {
      int xx = x - 1;
      float v = 0.f;
      if (yy >= 0 && yy < HH && xx >= 0 && xx < WW) v = img[yy * WW + xx];
      rows[r][x] = v;
    }
  }
  __syncthreads();

  unsigned short* orow = g_feats + ((size_t)(bv * HH + y) * WW) * CCH + c;
  for (int x = 0; x < WW; ++x) {
    float acc = bias;
#pragma unroll
    for (int r = 0; r < 3; ++r)
#pragma unroll
      for (int d = 0; d < 3; ++d)
        acc += rows[r][x + d] * w[r * 3 + d];
    acc = fmaxf(acc, 0.f);
    orow[(size_t)x * CCH] = f2b(acc);
  }
}

// ---- weight register set: 2 ftiles x 4 k-chunks (K=128) + biases -----------
struct WReg {
  ushort8 a[2][4];
  floatx4 bs[2];
};

__device__ __forceinline__ WReg wload(const unsigned short* __restrict__ Wt,
                                      const float* __restrict__ bias,
                                      int lane, int ftBase) {
  WReg w;
  const int col = lane & 15, quad = lane >> 4;
#pragma unroll
  for (int ftl = 0; ftl < 2; ++ftl) {
    const int ft = ftBase + ftl;
#pragma unroll
    for (int kk = 0; kk < 4; ++kk)
      w.a[ftl][kk] = *(const ushort8*)(Wt + (ft * 16 + col) * 128 + kk * 32 + quad * 8);
    w.bs[ftl] = *(const floatx4*)(bias + ft * 16 + quad * 4);
  }
  return w;
}

// ---- MFMA MLP compute (K=128), weights in registers ------------------------
// A=weights (m=out-feat), B=acts (n=row). D[m=ft*16+quad*4+r][n=ptt*16+col].
// MODE 0: relu+store; MODE 1: relu+residual+store; MODE 2: accumulate racc.
template<int MODE, int NPT>
__device__ __forceinline__ void mlp_c(
    const unsigned short* Act, int lda, const WReg& w,
    const unsigned short* Res, int ldr,
    unsigned short* Dst, int ldd,
    float* racc, int lane, int ftBase)
{
  const int col = lane & 15, quad = lane >> 4;
#pragma unroll
  for (int ptt = 0; ptt < NPT; ++ptt) {
    ushort8 bfr[4];
#pragma unroll
    for (int kk = 0; kk < 4; ++kk)
      bfr[kk] = *(const ushort8*)(Act + (ptt * 16 + col) * lda + kk * 32 + quad * 8);
#pragma unroll
    for (int ftl = 0; ftl < 2; ++ftl) {
      const int ft = ftBase + ftl;
      floatx4 acc = {0.f, 0.f, 0.f, 0.f};
#pragma unroll
      for (int kk = 0; kk < 4; ++kk)
        acc = __builtin_amdgcn_mfma_f32_16x16x32_bf16(
            __builtin_bit_cast(bf16x8, w.a[ftl][kk]),
            __builtin_bit_cast(bf16x8, bfr[kk]), acc, 0, 0, 0);
      const int row = ptt * 16 + col;
      if constexpr (MODE == 2) {
#pragma unroll
        for (int r = 0; r < 4; ++r)
          racc[ftl * 4 + r] += acc[r] + w.bs[ftl][r];
      } else {
        u16x4 rv;
        if constexpr (MODE == 1)
          rv = *(const u16x4*)(Res + row * ldr + ft * 16 + quad * 4);
        u16x4 o;
#pragma unroll
        for (int r = 0; r < 4; ++r) {
          float v = acc[r] + w.bs[ftl][r];
          if constexpr (MODE == 1) v += b2f(rv[r]);
          v = fmaxf(v, 0.f);
          o[r] = f2b(v);
        }
        *(u16x4*)(Dst + row * ldd + ft * 16 + quad * 4) = o;
      }
    }
  }
  __syncthreads();
}

// ---- first layer (K=160), self-loading weights -----------------------------
__device__ __forceinline__ void mlp_first(
    const unsigned short* Act, int lda,
    const unsigned short* __restrict__ Wt, const float* __restrict__ bias,
    unsigned short* Dst, int ldd, int lane, int ftBase)
{
  const int col = lane & 15, quad = lane >> 4;
  ushort8 afr[2][5];
  floatx4 bs4[2];
#pragma unroll
  for (int ftl = 0; ftl < 2; ++ftl) {
    const int ft = ftBase + ftl;
#pragma unroll
    for (int kk = 0; kk < 5; ++kk)
      afr[ftl][kk] = *(const ushort8*)(Wt + (ft * 16 + col) * 160 + kk * 32 + quad * 8);
    bs4[ftl] = *(const floatx4*)(bias + ft * 16 + quad * 4);
  }
#pragma unroll
  for (int ptt = 0; ptt < 4; ++ptt) {
    ushort8 bfr[5];
#pragma unroll
    for (int kk = 0; kk < 5; ++kk)
      bfr[kk] = *(const ushort8*)(Act + (ptt * 16 + col) * lda + kk * 32 + quad * 8);
#pragma unroll
    for (int ftl = 0; ftl < 2; ++ftl) {
      const int ft = ftBase + ftl;
      floatx4 acc = {0.f, 0.f, 0.f, 0.f};
#pragma unroll
      for (int kk = 0; kk < 5; ++kk)
        acc = __builtin_amdgcn_mfma_f32_16x16x32_bf16(
            __builtin_bit_cast(bf16x8, afr[ftl][kk]),
            __builtin_bit_cast(bf16x8, bfr[kk]), acc, 0, 0, 0);
      const int row = ptt * 16 + col;
      u16x4 o;
#pragma unroll
      for (int r = 0; r < 4; ++r)
        o[r] = f2b(fmaxf(acc[r] + bs4[ftl][r], 0.f));
      *(u16x4*)(Dst + row * ldd + ft * 16 + quad * 4) = o;
    }
  }
  __syncthreads();
}

// ---- main: 4-view-batched + explicit weight-prefetch pipeline --------------
// 8192 blocks x 256 thr (4 waves), 16 pts/block; rows = (view,point), 64 rows.
// launch_bounds(256,4): 4 blocks/CU (LDS 38.9KB x4 = 155.6 <= 160KB).
__global__ __launch_bounds__(256, 4) void mvct_main(
    const float* __restrict__ angles, const int* __restrict__ idx,
    const unsigned short* __restrict__ wbuf,
    const float* __restrict__ vb_in, const float* __restrict__ vb1,
    const float* __restrict__ vb2, const float* __restrict__ vb_out,
    const float* __restrict__ gb_in, const float* __restrict__ gb1,
    const float* __restrict__ gb2, const float* __restrict__ gw_out,
    const float* __restrict__ gb_out,
    float* __restrict__ out)
{
  __shared__ __align__(16) unsigned short X[64][168];
  __shared__ __align__(16) unsigned short Hb[64][136];
  const int tid = threadIdx.x;
  const int lane = tid & 63;
  const int ftBase = (tid >> 6) * 2;           // wave w: ftiles 2w, 2w+1
  const int b = blockIdx.x >> 12;              // 4096 groups per batch
  const int pts0 = (blockIdx.x & 4095) * 16;

  const unsigned short* w_in_t   = wbuf;
  const unsigned short* vw1_t    = wbuf + 20480;
  const unsigned short* vw2_t    = wbuf + 69632;
  const unsigned short* vw_out_t = wbuf + 118784;
  const unsigned short* gw_in_t  = wbuf + 135168;
  const unsigned short* gw1_t    = wbuf + 151552;
  const unsigned short* gw2_t    = wbuf + 184320;

  const float inv = 2.0f / 127.0f;
  const int col = lane & 15, quad = lane >> 4;

  // Hoisted: L1/L2 weight loads overlap the whole sampling phase.
  WReg wA = wload(vw1_t, vb1, lane, ftBase);                       // L1
  WReg wB = wload(vw2_t, vb2, lane, ftBase);                       // L2

  // PE into X rows 0..63 cols 128..159 (per-row point p = row&15)
  if (tid < 64) {
    int p = tid & 15;
    int id = idx[pts0 + p];
    int iz = (id >> 14) & 127, iy = (id >> 7) & 127, ix = id & 127;
    float x = ix * inv - 1.f, y = iy * inv - 1.f, z = iz * inv - 1.f;
    const float PI = 3.14159265358979323846f;
    float pe[9] = {z, y, x, sinf(PI * z), sinf(PI * y), sinf(PI * x),
                   cosf(PI * z), cosf(PI * y), cosf(PI * x)};
#pragma unroll
    for (int j = 0; j < 9; ++j) X[tid][128 + j] = f2b(pe[j]);
    for (int j = 137; j < 160; ++j) X[tid][j] = 0;
  }

  // sampling: 4 iters; iter v: thread -> (p = tid>>4 & 15, cg = tid&15)
  for (int v = 0; v < VV; ++v) {
    const int bv = b * VV + v;
    const float ang = angles[bv];
    const float ct = cosf(ang), st = sinf(ang);
    const int p = (tid >> 4) & 15, cg = tid & 15;
    int id = idx[pts0 + p];
    int iz = (id >> 14) & 127, iy = (id >> 7) & 127, ix = id & 127;
    float x = ix * inv - 1.f, y = iy * inv - 1.f, z = iz * inv - 1.f;
    float u = x * ct - y * st;
    float px = (u + 1.f) * 127.5f, py = (z + 1.f) * 127.5f;
    px = fminf(fmaxf(px, 0.f), 255.f);
    py = fminf(fmaxf(py, 0.f), 255.f);
    int x0 = min((int)px, 254), y0 = min((int)py, 254);
    float wx = px - (float)x0, wy = py - (float)y0;
    const unsigned short* bp =
        g_feats + ((size_t)((bv * HH + y0) * WW + x0)) * CCH + cg * 8;
    ushort8 q00 = *(const ushort8*)bp;
    ushort8 q01 = *(const ushort8*)(bp + CCH);
    ushort8 q10 = *(const ushort8*)(bp + WW * CCH);
    ushort8 q11 = *(const ushort8*)(bp + WW * CCH + CCH);
    float w00 = (1.f - wx) * (1.f - wy), w01 = wx * (1.f - wy);
    float w10 = (1.f - wx) * wy, w11 = wx * wy;
    ushort8 o;
#pragma unroll
    for (int j = 0; j < 8; ++j) {
      float f = w00 * b2f(q00[j]) + w01 * b2f(q01[j]) +
                w10 * b2f(q10[j]) + w11 * b2f(q11[j]);
      o[j] = f2b(f);
    }
    *(ushort8*)&X[v * 16 + p][cg * 8] = o;
  }
  __syncthreads();

  float racc[8];
#pragma unroll
  for (int i = 0; i < 8; ++i) racc[i] = 0.f;

  // Explicit software pipeline: wload(L+1) issues right after the previous
  // barrier and overlaps layer L's MFMA.
  mlp_first(&X[0][0], 168, w_in_t, vb_in, &Hb[0][0], 136, lane, ftBase);  // L0
  mlp_c<0, 4>(&Hb[0][0], 136, wA, nullptr, 0, &X[0][0], 168, nullptr,
              lane, ftBase);                                        // L1
  wA = wload(vw1_t + 16384, vb1 + 128, lane, ftBase);              // L3
  mlp_c<1, 4>(&X[0][0], 168, wB, &Hb[0][0], 136, &Hb[0][0], 136, nullptr,
              lane, ftBase);                                        // L2
  wB = wload(vw2_t + 16384, vb2 + 128, lane, ftBase);              // L4
  mlp_c<0, 4>(&Hb[0][0], 136, wA, nullptr, 0, &X[0][0], 168, nullptr,
              lane, ftBase);                                        // L3
  wA = wload(vw1_t + 32768, vb1 + 256, lane, ftBase);              // L5
  mlp_c<1, 4>(&X[0][0], 168, wB, &Hb[0][0], 136, &Hb[0][0], 136, nullptr,
              lane, ftBase);                                        // L4
  wB = wload(vw2_t + 32768, vb2 + 256, lane, ftBase);              // L6
  mlp_c<0, 4>(&Hb[0][0], 136, wA, nullptr, 0, &X[0][0], 168, nullptr,
              lane, ftBase);                                        // L5
  wA = wload(vw_out_t, vb_out, lane, ftBase);                      // L7
  mlp_c<1, 4>(&X[0][0], 168, wB, &Hb[0][0], 136, &Hb[0][0], 136, nullptr,
              lane, ftBase);                                        // L6
  wB = wload(gw_in_t, gb_in, lane, ftBase);                        // G0
  mlp_c<2, 4>(&Hb[0][0], 136, wA, nullptr, 0, nullptr, 0, racc,
              lane, ftBase);                                        // L7 acc

  // mean over views -> X rows 0..15 cols 0..127
#pragma unroll
  for (int ftl = 0; ftl < 2; ++ftl) {
    u16x4 o;
#pragma unroll
    for (int r = 0; r < 4; ++r)
      o[r] = f2b(racc[ftl * 4 + r] * 0.25f);
    *(u16x4*)(&X[col][(ftBase + ftl) * 16 + quad * 4]) = o;
  }
  __syncthreads();

  wA = wload(gw1_t, gb1, lane, ftBase);                            // G1
  mlp_c<0, 1>(&X[0][0], 168, wB, nullptr, 0, &Hb[0][0], 136, nullptr,
              lane, ftBase);                                        // G0
  wB = wload(gw2_t, gb2, lane, ftBase);                            // G2
  mlp_c<0, 1>(&Hb[0][0], 136, wA, nullptr, 0, &X[0][0], 168, nullptr,
              lane, ftBase);                                        // G1
  wA = wload(gw1_t + 16384, gb1 + 128, lane, ftBase);              // G3
  mlp_c<1, 1>(&X[0][0], 168, wB, &Hb[0][0], 136, &Hb[0][0], 136, nullptr,
              lane, ftBase);                                        // G2
  wB = wload(gw2_t + 16384, gb2 + 128, lane, ftBase);              // G4
  mlp_c<0, 1>(&Hb[0][0], 136, wA, nullptr, 0, &X[0][0], 168, nullptr,
              lane, ftBase);                                        // G3
  mlp_c<1, 1>(&X[0][0], 168, wB, &Hb[0][0], 136, &Hb[0][0], 136, nullptr,
              lane, ftBase);                                        // G4

  // out = h @ gw_out + gb_out; 16 points, 4 lanes/point (wave 0)
  if (tid < 64) {
    const int p = tid & 15, q4 = tid >> 4;
    float s = 0.f;
    const unsigned short* hr = &Hb[p][q4 * 32];
    const float* wo = gw_out + q4 * 32;
#pragma unroll
    for (int c = 0; c < 32; ++c)
      s += b2f(hr[c]) * wo[c];
    s += __shfl_xor(s, 16, 64);
    s += __shfl_xor(s, 32, 64);
    if (q4 == 0)
      out[(size_t)b * NPTSC + pts0 + p] = s + gb_out[0];
  }
}

extern "C" void kernel_launch(void* const* d_in, const int* in_sizes, int n_in,
                              void* d_out, int out_size, void* d_ws, size_t ws_size,
                              hipStream_t stream) {
  const float* views  = (const float*)d_in[0];
  const float* angles = (const float*)d_in[1];
  const int*   idx    = (const int*)d_in[2];
  const float* conv_w = (const float*)d_in[3];
  const float* conv_b = (const float*)d_in[4];
  const float* vw_in  = (const float*)d_in[5];
  const float* vb_in  = (const float*)d_in[6];
  const float* vw1    = (const float*)d_in[7];
  const float* vb1    = (const float*)d_in[8];
  const float* vw2    = (const float*)d_in[9];
  const float* vb2    = (const float*)d_in[10];
  const float* vw_out = (const float*)d_in[11];
  const float* vb_out = (const float*)d_in[12];
  const float* gw_in  = (const float*)d_in[13];
  const float* gb_in  = (const float*)d_in[14];
  const float* gw1    = (const float*)d_in[15];
  const float* gb1    = (const float*)d_in[16];
  const float* gw2    = (const float*)d_in[17];
  const float* gb2    = (const float*)d_in[18];
  const float* gw_out = (const float*)d_in[19];
  const float* gb_out = (const float*)d_in[20];

  unsigned short* wbuf = (unsigned short*)d_ws;  // 434 KB

  hipLaunchKernelGGL(mvct_prep, dim3(848), dim3(256), 0, stream,
                     vw_in, vw1, vw2, vw_out, gw_in, gw1, gw2, wbuf);
  hipLaunchKernelGGL(mvct_conv, dim3(BB * VV * HH), dim3(128), 0, stream,
                     views, conv_w, conv_b);
  hipLaunchKernelGGL(mvct_main, dim3(BB * (NPTSC / 16)), dim3(256), 0, stream,
                     angles, idx, wbuf, vb_in, vb1, vb2, vb_out,
                     gb_in, gb1, gb2, gw_out, gb_out,
                     (float*)d_out);
}

// Round 26
// 574.214 us; speedup vs baseline: 2.1130x; 1.0818x over previous
//
#include <hip/hip_runtime.h>
#include <math.h>

#define BB 2
#define VV 4
#define NPTSC 65536
#define HH 256
#define WW 256
#define CCH 128

typedef __attribute__((ext_vector_type(8))) unsigned short ushort8;
typedef __attribute__((ext_vector_type(4))) unsigned short u16x4;
typedef __attribute__((ext_vector_type(8))) __bf16 bf16x8;
typedef __attribute__((ext_vector_type(4))) float floatx4;

// Static feats buffer (128 MiB); rewritten fully every launch.
__device__ unsigned short g_feats[(size_t)BB * VV * HH * WW * CCH];

__device__ __forceinline__ float b2f(unsigned short u) {
  unsigned int x = ((unsigned int)u) << 16;
  return __builtin_bit_cast(float, x);
}
__device__ __forceinline__ unsigned short f2b(float f) {
  unsigned int x = __builtin_bit_cast(unsigned int, f);
  x = x + 0x7fffu + ((x >> 16) & 1u);
  return (unsigned short)(x >> 16);
}

// ---- prep: f32 weights -> bf16 [out][in] into d_ws (434 KB) ----------------
__global__ __launch_bounds__(256) void mvct_prep(
    const float* __restrict__ vw_in, const float* __restrict__ vw1,
    const float* __restrict__ vw2, const float* __restrict__ vw_out,
    const float* __restrict__ gw_in, const float* __restrict__ gw1,
    const float* __restrict__ gw2, unsigned short* __restrict__ wbuf)
{
  int tid = blockIdx.x * 256 + threadIdx.x;
  if (tid >= 217088) return;
  float val;
  if (tid < 20480) {
    int n = tid / 160, k = tid - n * 160;
    val = (k < 137) ? vw_in[k * 128 + n] : 0.f;
  } else {
    int t = tid - 20480;
    const float* src;
    if (t < 49152) { src = vw1; }
    else if (t < 98304) { t -= 49152; src = vw2; }
    else if (t < 114688) { t -= 98304; src = vw_out; }
    else if (t < 131072) { t -= 114688; src = gw_in; }
    else if (t < 163840) { t -= 131072; src = gw1; }
    else { t -= 163840; src = gw2; }
    int i = t >> 14; int r = t & 16383; int n = r >> 7; int k = r & 127;
    val = src[i * 16384 + k * 128 + n];
  }
  wbuf[tid] = f2b(val);
}

// ---- conv 3x3 SAME, 1->128 ch, relu, channel-last bf16 into g_feats --------
__global__ __launch_bounds__(128) void mvct_conv(
    const float* __restrict__ views, const float* __restrict__ conv_w,
    const float* __restrict__ conv_b)
{
  int bv = blockIdx.x >> 8;
  int y = blockIdx.x & 255;
  int c = threadIdx.x;
  float w[9];
#pragma unroll
  for (int j = 0; j < 9; ++j) w[j] = conv_w[c * 9 + j];
  float bias = conv_b[c];

  __shared__ float rows[3][258];
  const float* img = views + (size_t)bv * HH * WW;
#pragma unroll
  for (int r = 0; r < 3; ++r) {
    int yy = y - 1 + r;
    for (int x = c; x < 258; x += 128) {
      int xx = x - 1;
      float v = 0.f;
      if (yy >= 0 && yy < HH && xx >= 0 && xx < WW) v = img[yy * WW + xx];
      rows[r][x] = v;
    }
  }
  __syncthreads();

  unsigned short* orow = g_feats + ((size_t)(bv * HH + y) * WW) * CCH + c;
  for (int x = 0; x < WW; ++x) {
    float acc = bias;
#pragma unroll
    for (int r = 0; r < 3; ++r)
#pragma unroll
      for (int d = 0; d < 3; ++d)
        acc += rows[r][x + d] * w[r * 3 + d];
    acc = fmaxf(acc, 0.f);
    orow[(size_t)x * CCH] = f2b(acc);
  }
}

// ---- weight register set: 2 ftiles x 4 k-chunks (K=128) + biases -----------
struct WReg {
  ushort8 a[2][4];
  floatx4 bs[2];
};

__device__ __forceinline__ WReg wload(const unsigned short* __restrict__ Wt,
                                      const float* __restrict__ bias,
                                      int lane, int ftBase) {
  WReg w;
  const int col = lane & 15, quad = lane >> 4;
#pragma unroll
  for (int ftl = 0; ftl < 2; ++ftl) {
    const int ft = ftBase + ftl;
#pragma unroll
    for (int kk = 0; kk < 4; ++kk)
      w.a[ftl][kk] = *(const ushort8*)(Wt + (ft * 16 + col) * 128 + kk * 32 + quad * 8);
    w.bs[ftl] = *(const floatx4*)(bias + ft * 16 + quad * 4);
  }
  return w;
}

// ---- MFMA MLP compute (K=128), weights in registers ------------------------
// A=weights (m=out-feat), B=acts (n=row). D[m=ft*16+quad*4+r][n=ptt*16+col].
// MODE 0: relu+store; MODE 1: relu+residual+store; MODE 2: accumulate racc.
template<int MODE, int NPT>
__device__ __forceinline__ void mlp_c(
    const unsigned short* Act, int lda, const WReg& w,
    const unsigned short* Res, int ldr,
    unsigned short* Dst, int ldd,
    float* racc, int lane, int ftBase)
{
  const int col = lane & 15, quad = lane >> 4;
#pragma unroll
  for (int ptt = 0; ptt < NPT; ++ptt) {
    ushort8 bfr[4];
#pragma unroll
    for (int kk = 0; kk < 4; ++kk)
      bfr[kk] = *(const ushort8*)(Act + (ptt * 16 + col) * lda + kk * 32 + quad * 8);
#pragma unroll
    for (int ftl = 0; ftl < 2; ++ftl) {
      const int ft = ftBase + ftl;
      floatx4 acc = {0.f, 0.f, 0.f, 0.f};
#pragma unroll
      for (int kk = 0; kk < 4; ++kk)
        acc = __builtin_amdgcn_mfma_f32_16x16x32_bf16(
            __builtin_bit_cast(bf16x8, w.a[ftl][kk]),
            __builtin_bit_cast(bf16x8, bfr[kk]), acc, 0, 0, 0);
      const int row = ptt * 16 + col;
      if constexpr (MODE == 2) {
#pragma unroll
        for (int r = 0; r < 4; ++r)
          racc[ftl * 4 + r] += acc[r] + w.bs[ftl][r];
      } else {
        u16x4 rv;
        if constexpr (MODE == 1)
          rv = *(const u16x4*)(Res + row * ldr + ft * 16 + quad * 4);
        u16x4 o;
#pragma unroll
        for (int r = 0; r < 4; ++r) {
          float v = acc[r] + w.bs[ftl][r];
          if constexpr (MODE == 1) v += b2f(rv[r]);
          v = fmaxf(v, 0.f);
          o[r] = f2b(v);
        }
        *(u16x4*)(Dst + row * ldd + ft * 16 + quad * 4) = o;
      }
    }
  }
  __syncthreads();
}

// ---- first layer (K=160), self-loading weights -----------------------------
__device__ __forceinline__ void mlp_first(
    const unsigned short* Act, int lda,
    const unsigned short* __restrict__ Wt, const float* __restrict__ bias,
    unsigned short* Dst, int ldd, int lane, int ftBase)
{
  const int col = lane & 15, quad = lane >> 4;
  ushort8 afr[2][5];
  floatx4 bs4[2];
#pragma unroll
  for (int ftl = 0; ftl < 2; ++ftl) {
    const int ft = ftBase + ftl;
#pragma unroll
    for (int kk = 0; kk < 5; ++kk)
      afr[ftl][kk] = *(const ushort8*)(Wt + (ft * 16 + col) * 160 + kk * 32 + quad * 8);
    bs4[ftl] = *(const floatx4*)(bias + ft * 16 + quad * 4);
  }
#pragma unroll
  for (int ptt = 0; ptt < 4; ++ptt) {
    ushort8 bfr[5];
#pragma unroll
    for (int kk = 0; kk < 5; ++kk)
      bfr[kk] = *(const ushort8*)(Act + (ptt * 16 + col) * lda + kk * 32 + quad * 8);
#pragma unroll
    for (int ftl = 0; ftl < 2; ++ftl) {
      const int ft = ftBase + ftl;
      floatx4 acc = {0.f, 0.f, 0.f, 0.f};
#pragma unroll
      for (int kk = 0; kk < 5; ++kk)
        acc = __builtin_amdgcn_mfma_f32_16x16x32_bf16(
            __builtin_bit_cast(bf16x8, afr[ftl][kk]),
            __builtin_bit_cast(bf16x8, bfr[kk]), acc, 0, 0, 0);
      const int row = ptt * 16 + col;
      u16x4 o;
#pragma unroll
      for (int r = 0; r < 4; ++r)
        o[r] = f2b(fmaxf(acc[r] + bs4[ftl][r], 0.f));
      *(u16x4*)(Dst + row * ldd + ft * 16 + quad * 4) = o;
    }
  }
  __syncthreads();
}

// ---- main: 4-view-batched + explicit weight-prefetch pipeline --------------
// 8192 blocks x 256 thr (4 waves), 16 pts/block; rows = (view,point), 64 rows.
// launch_bounds(256,4): 4 blocks/CU (LDS 38.9KB x4 = 155.6 <= 160KB).
// NOTE: wloads stay AFTER the sampling phase (hoisting them spilled in R25).
__global__ __launch_bounds__(256, 4) void mvct_main(
    const float* __restrict__ angles, const int* __restrict__ idx,
    const unsigned short* __restrict__ wbuf,
    const float* __restrict__ vb_in, const float* __restrict__ vb1,
    const float* __restrict__ vb2, const float* __restrict__ vb_out,
    const float* __restrict__ gb_in, const float* __restrict__ gb1,
    const float* __restrict__ gb2, const float* __restrict__ gw_out,
    const float* __restrict__ gb_out,
    float* __restrict__ out)
{
  __shared__ __align__(16) unsigned short X[64][168];
  __shared__ __align__(16) unsigned short Hb[64][136];
  const int tid = threadIdx.x;
  const int lane = tid & 63;
  const int ftBase = (tid >> 6) * 2;           // wave w: ftiles 2w, 2w+1
  const int b = blockIdx.x >> 12;              // 4096 groups per batch
  const int pts0 = (blockIdx.x & 4095) * 16;

  const unsigned short* w_in_t   = wbuf;
  const unsigned short* vw1_t    = wbuf + 20480;
  const unsigned short* vw2_t    = wbuf + 69632;
  const unsigned short* vw_out_t = wbuf + 118784;
  const unsigned short* gw_in_t  = wbuf + 135168;
  const unsigned short* gw1_t    = wbuf + 151552;
  const unsigned short* gw2_t    = wbuf + 184320;

  const float inv = 2.0f / 127.0f;
  const int col = lane & 15, quad = lane >> 4;

  // PE into X rows 0..63 cols 128..159 (per-row point p = row&15)
  if (tid < 64) {
    int p = tid & 15;
    int id = idx[pts0 + p];
    int iz = (id >> 14) & 127, iy = (id >> 7) & 127, ix = id & 127;
    float x = ix * inv - 1.f, y = iy * inv - 1.f, z = iz * inv - 1.f;
    const float PI = 3.14159265358979323846f;
    float pe[9] = {z, y, x, sinf(PI * z), sinf(PI * y), sinf(PI * x),
                   cosf(PI * z), cosf(PI * y), cosf(PI * x)};
#pragma unroll
    for (int j = 0; j < 9; ++j) X[tid][128 + j] = f2b(pe[j]);
    for (int j = 137; j < 160; ++j) X[tid][j] = 0;
  }

  // sampling: 4 iters; iter v: thread -> (p = tid>>4 & 15, cg = tid&15)
  for (int v = 0; v < VV; ++v) {
    const int bv = b * VV + v;
    const float ang = angles[bv];
    const float ct = cosf(ang), st = sinf(ang);
    const int p = (tid >> 4) & 15, cg = tid & 15;
    int id = idx[pts0 + p];
    int iz = (id >> 14) & 127, iy = (id >> 7) & 127, ix = id & 127;
    float x = ix * inv - 1.f, y = iy * inv - 1.f, z = iz * inv - 1.f;
    float u = x * ct - y * st;
    float px = (u + 1.f) * 127.5f, py = (z + 1.f) * 127.5f;
    px = fminf(fmaxf(px, 0.f), 255.f);
    py = fminf(fmaxf(py, 0.f), 255.f);
    int x0 = min((int)px, 254), y0 = min((int)py, 254);
    float wx = px - (float)x0, wy = py - (float)y0;
    const unsigned short* bp =
        g_feats + ((size_t)((bv * HH + y0) * WW + x0)) * CCH + cg * 8;
    ushort8 q00 = *(const ushort8*)bp;
    ushort8 q01 = *(const ushort8*)(bp + CCH);
    ushort8 q10 = *(const ushort8*)(bp + WW * CCH);
    ushort8 q11 = *(const ushort8*)(bp + WW * CCH + CCH);
    float w00 = (1.f - wx) * (1.f - wy), w01 = wx * (1.f - wy);
    float w10 = (1.f - wx) * wy, w11 = wx * wy;
    ushort8 o;
#pragma unroll
    for (int j = 0; j < 8; ++j) {
      float f = w00 * b2f(q00[j]) + w01 * b2f(q01[j]) +
                w10 * b2f(q10[j]) + w11 * b2f(q11[j]);
      o[j] = f2b(f);
    }
    *(ushort8*)&X[v * 16 + p][cg * 8] = o;
  }
  __syncthreads();

  float racc[8];
#pragma unroll
  for (int i = 0; i < 8; ++i) racc[i] = 0.f;

  // Explicit software pipeline: wload(L+1) issues right after the previous
  // barrier and overlaps layer L's MFMA. By-value WReg, no pointers.
  WReg wA = wload(vw1_t, vb1, lane, ftBase);                       // L1
  mlp_first(&X[0][0], 168, w_in_t, vb_in, &Hb[0][0], 136, lane, ftBase);  // L0
  WReg wB = wload(vw2_t, vb2, lane, ftBase);                       // L2
  mlp_c<0, 4>(&Hb[0][0], 136, wA, nullptr, 0, &X[0][0], 168, nullptr,
              lane, ftBase);                                        // L1
  wA = wload(vw1_t + 16384, vb1 + 128, lane, ftBase);              // L3
  mlp_c<1, 4>(&X[0][0], 168, wB, &Hb[0][0], 136, &Hb[0][0], 136, nullptr,
              lane, ftBase);                                        // L2
  wB = wload(vw2_t + 16384, vb2 + 128, lane, ftBase);              // L4
  mlp_c<0, 4>(&Hb[0][0], 136, wA, nullptr, 0, &X[0][0], 168, nullptr,
              lane, ftBase);                                        // L3
  wA = wload(vw1_t + 32768, vb1 + 256, lane, ftBase);              // L5
  mlp_c<1, 4>(&X[0][0], 168, wB, &Hb[0][0], 136, &Hb[0][0], 136, nullptr,
              lane, ftBase);                                        // L4
  wB = wload(vw2_t + 32768, vb2 + 256, lane, ftBase);              // L6
  mlp_c<0, 4>(&Hb[0][0], 136, wA, nullptr, 0, &X[0][0], 168, nullptr,
              lane, ftBase);                                        // L5
  wA = wload(vw_out_t, vb_out, lane, ftBase);                      // L7
  mlp_c<1, 4>(&X[0][0], 168, wB, &Hb[0][0], 136, &Hb[0][0], 136, nullptr,
              lane, ftBase);                                        // L6
  wB = wload(gw_in_t, gb_in, lane, ftBase);                        // G0
  mlp_c<2, 4>(&Hb[0][0], 136, wA, nullptr, 0, nullptr, 0, racc,
              lane, ftBase);                                        // L7 acc

  // mean over views -> X rows 0..15 cols 0..127
#pragma unroll
  for (int ftl = 0; ftl < 2; ++ftl) {
    u16x4 o;
#pragma unroll
    for (int r = 0; r < 4; ++r)
      o[r] = f2b(racc[ftl * 4 + r] * 0.25f);
    *(u16x4*)(&X[col][(ftBase + ftl) * 16 + quad * 4]) = o;
  }
  __syncthreads();

  wA = wload(gw1_t, gb1, lane, ftBase);                            // G1
  mlp_c<0, 1>(&X[0][0], 168, wB, nullptr, 0, &Hb[0][0], 136, nullptr,
              lane, ftBase);                                        // G0
  wB = wload(gw2_t, gb2, lane, ftBase);                            // G2
  mlp_c<0, 1>(&Hb[0][0], 136, wA, nullptr, 0, &X[0][0], 168, nullptr,
              lane, ftBase);                                        // G1
  wA = wload(gw1_t + 16384, gb1 + 128, lane, ftBase);              // G3
  mlp_c<1, 1>(&X[0][0], 168, wB, &Hb[0][0], 136, &Hb[0][0], 136, nullptr,
              lane, ftBase);                                        // G2
  wB = wload(gw2_t + 16384, gb2 + 128, lane, ftBase);              // G4
  mlp_c<0, 1>(&Hb[0][0], 136, wA, nullptr, 0, &X[0][0], 168, nullptr,
              lane, ftBase);                                        // G3
  mlp_c<1, 1>(&X[0][0], 168, wB, &Hb[0][0], 136, &Hb[0][0], 136, nullptr,
              lane, ftBase);                                        // G4

  // out = h @ gw_out + gb_out; 16 points, 4 lanes/point (wave 0)
  if (tid < 64) {
    const int p = tid & 15, q4 = tid >> 4;
    float s = 0.f;
    const unsigned short* hr = &Hb[p][q4 * 32];
    const float* wo = gw_out + q4 * 32;
#pragma unroll
    for (int c = 0; c < 32; ++c)
      s += b2f(hr[c]) * wo[c];
    s += __shfl_xor(s, 16, 64);
    s += __shfl_xor(s, 32, 64);
    if (q4 == 0)
      out[(size_t)b * NPTSC + pts0 + p] = s + gb_out[0];
  }
}

extern "C" void kernel_launch(void* const* d_in, const int* in_sizes, int n_in,
                              void* d_out, int out_size, void* d_ws, size_t ws_size,
                              hipStream_t stream) {
  const float* views  = (const float*)d_in[0];
  const float* angles = (const float*)d_in[1];
  const int*   idx    = (const int*)d_in[2];
  const float* conv_w = (const float*)d_in[3];
  const float* conv_b = (const float*)d_in[4];
  const float* vw_in  = (const float*)d_in[5];
  const float* vb_in  = (const float*)d_in[6];
  const float* vw1    = (const float*)d_in[7];
  const float* vb1    = (const float*)d_in[8];
  const float* vw2    = (const float*)d_in[9];
  const float* vb2    = (const float*)d_in[10];
  const float* vw_out = (const float*)d_in[11];
  const float* vb_out = (const float*)d_in[12];
  const float* gw_in  = (const float*)d_in[13];
  const float* gb_in  = (const float*)d_in[14];
  const float* gw1    = (const float*)d_in[15];
  const float* gb1    = (const float*)d_in[16];
  const float* gw2    = (const float*)d_in[17];
  const float* gb2    = (const float*)d_in[18];
  const float* gw_out = (const float*)d_in[19];
  const float* gb_out = (const float*)d_in[20];

  unsigned short* wbuf = (unsigned short*)d_ws;  // 434 KB

  hipLaunchKernelGGL(mvct_prep, dim3(848), dim3(256), 0, stream,
                     vw_in, vw1, vw2, vw_out, gw_in, gw1, gw2, wbuf);
  hipLaunchKernelGGL(mvct_conv, dim3(BB * VV * HH), dim3(128), 0, stream,
                     views, conv_w, conv_b);
  hipLaunchKernelGGL(mvct_main, dim3(BB * (NPTSC / 16)), dim3(256), 0, stream,
                     angles, idx, wbuf, vb_in, vb1, vb2, vb_out,
                     gb_in, gb1, gb2, gw_out, gb_out,
                     (float*)d_out);
}

// Round 27
// 539.638 us; speedup vs baseline: 2.2484x; 1.0641x over previous
//
#include <hip/hip_runtime.h>
#include <math.h>

#define BB 2
#define VV 4
#define NPTSC 65536
#define HH 256
#define WW 256
#define CCH 128

typedef __attribute__((ext_vector_type(8))) unsigned short ushort8;
typedef __attribute__((ext_vector_type(4))) unsigned short u16x4;
typedef __attribute__((ext_vector_type(8))) __bf16 bf16x8;
typedef __attribute__((ext_vector_type(4))) float floatx4;

// Static feats buffer (128 MiB); rewritten fully every launch.
__device__ unsigned short g_feats[(size_t)BB * VV * HH * WW * CCH];

__device__ __forceinline__ float b2f(unsigned short u) {
  unsigned int x = ((unsigned int)u) << 16;
  return __builtin_bit_cast(float, x);
}
__device__ __forceinline__ unsigned short f2b(float f) {
  unsigned int x = __builtin_bit_cast(unsigned int, f);
  x = x + 0x7fffu + ((x >> 16) & 1u);
  return (unsigned short)(x >> 16);
}

// ---- prep: f32 weights -> bf16 [out][in] into d_ws (434 KB) ----------------
__global__ __launch_bounds__(256) void mvct_prep(
    const float* __restrict__ vw_in, const float* __restrict__ vw1,
    const float* __restrict__ vw2, const float* __restrict__ vw_out,
    const float* __restrict__ gw_in, const float* __restrict__ gw1,
    const float* __restrict__ gw2, unsigned short* __restrict__ wbuf)
{
  int tid = blockIdx.x * 256 + threadIdx.x;
  if (tid >= 217088) return;
  float val;
  if (tid < 20480) {
    int n = tid / 160, k = tid - n * 160;
    val = (k < 137) ? vw_in[k * 128 + n] : 0.f;
  } else {
    int t = tid - 20480;
    const float* src;
    if (t < 49152) { src = vw1; }
    else if (t < 98304) { t -= 49152; src = vw2; }
    else if (t < 114688) { t -= 98304; src = vw_out; }
    else if (t < 131072) { t -= 114688; src = gw_in; }
    else if (t < 163840) { t -= 131072; src = gw1; }
    else { t -= 163840; src = gw2; }
    int i = t >> 14; int r = t & 16383; int n = r >> 7; int k = r & 127;
    val = src[i * 16384 + k * 128 + n];
  }
  wbuf[tid] = f2b(val);
}

// ---- conv 3x3 SAME, 1->128 ch, relu, channel-last bf16 into g_feats --------
__global__ __launch_bounds__(128) void mvct_conv(
    const float* __restrict__ views, const float* __restrict__ conv_w,
    const float* __restrict__ conv_b)
{
  int bv = blockIdx.x >> 8;
  int y = blockIdx.x & 255;
  int c = threadIdx.x;
  float w[9];
#pragma unroll
  for (int j = 0; j < 9; ++j) w[j] = conv_w[c * 9 + j];
  float bias = conv_b[c];

  __shared__ float rows[3][258];
  const float* img = views + (size_t)bv * HH * WW;
#pragma unroll
  for (int r = 0; r < 3; ++r) {
    int yy = y - 1 + r;
    for (int x = c; x < 258; x += 128) {
      int xx = x - 1;
      float v = 0.f;
      if (yy >= 0 && yy < HH && xx >= 0 && xx < WW) v = img[yy * WW + xx];
      rows[r][x] = v;
    }
  }
  __syncthreads();

  unsigned short* orow = g_feats + ((size_t)(bv * HH + y) * WW) * CCH + c;
  for (int x = 0; x < WW; ++x) {
    float acc = bias;
#pragma unroll
    for (int r = 0; r < 3; ++r)
#pragma unroll
      for (int d = 0; d < 3; ++d)
        acc += rows[r][x + d] * w[r * 3 + d];
    acc = fmaxf(acc, 0.f);
    orow[(size_t)x * CCH] = f2b(acc);
  }
}

// ---- weight register set: 2 ftiles x 4 k-chunks (K=128) + biases -----------
struct WReg {
  ushort8 a[2][4];
  floatx4 bs[2];
};

__device__ __forceinline__ WReg wload(const unsigned short* __restrict__ Wt,
                                      const float* __restrict__ bias,
                                      int lane, int ftBase) {
  WReg w;
  const int col = lane & 15, quad = lane >> 4;
#pragma unroll
  for (int ftl = 0; ftl < 2; ++ftl) {
    const int ft = ftBase + ftl;
#pragma unroll
    for (int kk = 0; kk < 4; ++kk)
      w.a[ftl][kk] = *(const ushort8*)(Wt + (ft * 16 + col) * 128 + kk * 32 + quad * 8);
    w.bs[ftl] = *(const floatx4*)(bias + ft * 16 + quad * 4);
  }
  return w;
}

// ---- MFMA MLP compute (K=128), weights in registers ------------------------
// A=weights (m=out-feat), B=acts (n=row). D[m=ft*16+quad*4+r][n=ptt*16+col].
// MODE 0: relu+store; MODE 1: relu+residual+store; MODE 2: accumulate racc.
template<int MODE, int NPT>
__device__ __forceinline__ void mlp_c(
    const unsigned short* Act, int lda, const WReg& w,
    const unsigned short* Res, int ldr,
    unsigned short* Dst, int ldd,
    float* racc, int lane, int ftBase)
{
  const int col = lane & 15, quad = lane >> 4;
#pragma unroll
  for (int ptt = 0; ptt < NPT; ++ptt) {
    ushort8 bfr[4];
#pragma unroll
    for (int kk = 0; kk < 4; ++kk)
      bfr[kk] = *(const ushort8*)(Act + (ptt * 16 + col) * lda + kk * 32 + quad * 8);
#pragma unroll
    for (int ftl = 0; ftl < 2; ++ftl) {
      const int ft = ftBase + ftl;
      floatx4 acc = {0.f, 0.f, 0.f, 0.f};
#pragma unroll
      for (int kk = 0; kk < 4; ++kk)
        acc = __builtin_amdgcn_mfma_f32_16x16x32_bf16(
            __builtin_bit_cast(bf16x8, w.a[ftl][kk]),
            __builtin_bit_cast(bf16x8, bfr[kk]), acc, 0, 0, 0);
      const int row = ptt * 16 + col;
      if constexpr (MODE == 2) {
#pragma unroll
        for (int r = 0; r < 4; ++r)
          racc[ftl * 4 + r] += acc[r] + w.bs[ftl][r];
      } else {
        u16x4 rv;
        if constexpr (MODE == 1)
          rv = *(const u16x4*)(Res + row * ldr + ft * 16 + quad * 4);
        u16x4 o;
#pragma unroll
        for (int r = 0; r < 4; ++r) {
          float v = acc[r] + w.bs[ftl][r];
          if constexpr (MODE == 1) v += b2f(rv[r]);
          v = fmaxf(v, 0.f);
          o[r] = f2b(v);
        }
        *(u16x4*)(Dst + row * ldd + ft * 16 + quad * 4) = o;
      }
    }
  }
  __syncthreads();
}

// ---- first layer (K=160), self-loading weights -----------------------------
__device__ __forceinline__ void mlp_first(
    const unsigned short* Act, int lda,
    const unsigned short* __restrict__ Wt, const float* __restrict__ bias,
    unsigned short* Dst, int ldd, int lane, int ftBase)
{
  const int col = lane & 15, quad = lane >> 4;
  ushort8 afr[2][5];
  floatx4 bs4[2];
#pragma unroll
  for (int ftl = 0; ftl < 2; ++ftl) {
    const int ft = ftBase + ftl;
#pragma unroll
    for (int kk = 0; kk < 5; ++kk)
      afr[ftl][kk] = *(const ushort8*)(Wt + (ft * 16 + col) * 160 + kk * 32 + quad * 8);
    bs4[ftl] = *(const floatx4*)(bias + ft * 16 + quad * 4);
  }
#pragma unroll
  for (int ptt = 0; ptt < 4; ++ptt) {
    ushort8 bfr[5];
#pragma unroll
    for (int kk = 0; kk < 5; ++kk)
      bfr[kk] = *(const ushort8*)(Act + (ptt * 16 + col) * lda + kk * 32 + quad * 8);
#pragma unroll
    for (int ftl = 0; ftl < 2; ++ftl) {
      const int ft = ftBase + ftl;
      floatx4 acc = {0.f, 0.f, 0.f, 0.f};
#pragma unroll
      for (int kk = 0; kk < 5; ++kk)
        acc = __builtin_amdgcn_mfma_f32_16x16x32_bf16(
            __builtin_bit_cast(bf16x8, afr[ftl][kk]),
            __builtin_bit_cast(bf16x8, bfr[kk]), acc, 0, 0, 0);
      const int row = ptt * 16 + col;
      u16x4 o;
#pragma unroll
      for (int r = 0; r < 4; ++r)
        o[r] = f2b(fmaxf(acc[r] + bs4[ftl][r], 0.f));
      *(u16x4*)(Dst + row * ldd + ft * 16 + quad * 4) = o;
    }
  }
  __syncthreads();
}

// ---- main: 4-view-batched + explicit weight-prefetch pipeline --------------
// 8192 blocks x 256 thr (4 waves), 16 pts/block; rows = (view,point), 64 rows.
// (256,3): best verified config — tighter bounds spill (R25/R26), looser idles.
__global__ __launch_bounds__(256, 3) void mvct_main(
    const float* __restrict__ angles, const int* __restrict__ idx,
    const unsigned short* __restrict__ wbuf,
    const float* __restrict__ vb_in, const float* __restrict__ vb1,
    const float* __restrict__ vb2, const float* __restrict__ vb_out,
    const float* __restrict__ gb_in, const float* __restrict__ gb1,
    const float* __restrict__ gb2, const float* __restrict__ gw_out,
    const float* __restrict__ gb_out,
    float* __restrict__ out)
{
  __shared__ __align__(16) unsigned short X[64][168];
  __shared__ __align__(16) unsigned short Hb[64][136];
  const int tid = threadIdx.x;
  const int lane = tid & 63;
  const int ftBase = (tid >> 6) * 2;           // wave w: ftiles 2w, 2w+1
  const int b = blockIdx.x >> 12;              // 4096 groups per batch
  const int pts0 = (blockIdx.x & 4095) * 16;

  const unsigned short* w_in_t   = wbuf;
  const unsigned short* vw1_t    = wbuf + 20480;
  const unsigned short* vw2_t    = wbuf + 69632;
  const unsigned short* vw_out_t = wbuf + 118784;
  const unsigned short* gw_in_t  = wbuf + 135168;
  const unsigned short* gw1_t    = wbuf + 151552;
  const unsigned short* gw2_t    = wbuf + 184320;

  const float inv = 2.0f / 127.0f;
  const int col = lane & 15, quad = lane >> 4;

  // PE into X rows 0..63 cols 128..159 (per-row point p = row&15)
  if (tid < 64) {
    int p = tid & 15;
    int id = idx[pts0 + p];
    int iz = (id >> 14) & 127, iy = (id >> 7) & 127, ix = id & 127;
    float x = ix * inv - 1.f, y = iy * inv - 1.f, z = iz * inv - 1.f;
    const float PI = 3.14159265358979323846f;
    float pe[9] = {z, y, x, sinf(PI * z), sinf(PI * y), sinf(PI * x),
                   cosf(PI * z), cosf(PI * y), cosf(PI * x)};
#pragma unroll
    for (int j = 0; j < 9; ++j) X[tid][128 + j] = f2b(pe[j]);
    for (int j = 137; j < 160; ++j) X[tid][j] = 0;
  }

  // sampling: 4 iters; iter v: thread -> (p = tid>>4 & 15, cg = tid&15)
  for (int v = 0; v < VV; ++v) {
    const int bv = b * VV + v;
    const float ang = angles[bv];
    const float ct = cosf(ang), st = sinf(ang);
    const int p = (tid >> 4) & 15, cg = tid & 15;
    int id = idx[pts0 + p];
    int iz = (id >> 14) & 127, iy = (id >> 7) & 127, ix = id & 127;
    float x = ix * inv - 1.f, y = iy * inv - 1.f, z = iz * inv - 1.f;
    float u = x * ct - y * st;
    float px = (u + 1.f) * 127.5f, py = (z + 1.f) * 127.5f;
    px = fminf(fmaxf(px, 0.f), 255.f);
    py = fminf(fmaxf(py, 0.f), 255.f);
    int x0 = min((int)px, 254), y0 = min((int)py, 254);
    float wx = px - (float)x0, wy = py - (float)y0;
    const unsigned short* bp =
        g_feats + ((size_t)((bv * HH + y0) * WW + x0)) * CCH + cg * 8;
    ushort8 q00 = *(const ushort8*)bp;
    ushort8 q01 = *(const ushort8*)(bp + CCH);
    ushort8 q10 = *(const ushort8*)(bp + WW * CCH);
    ushort8 q11 = *(const ushort8*)(bp + WW * CCH + CCH);
    float w00 = (1.f - wx) * (1.f - wy), w01 = wx * (1.f - wy);
    float w10 = (1.f - wx) * wy, w11 = wx * wy;
    ushort8 o;
#pragma unroll
    for (int j = 0; j < 8; ++j) {
      float f = w00 * b2f(q00[j]) + w01 * b2f(q01[j]) +
                w10 * b2f(q10[j]) + w11 * b2f(q11[j]);
      o[j] = f2b(f);
    }
    *(ushort8*)&X[v * 16 + p][cg * 8] = o;
  }
  __syncthreads();

  float racc[8];
#pragma unroll
  for (int i = 0; i < 8; ++i) racc[i] = 0.f;

  // Explicit software pipeline: wload(L+1) issues right after the previous
  // barrier and overlaps layer L's MFMA. By-value WReg, no pointers -> no spill.
  WReg wA = wload(vw1_t, vb1, lane, ftBase);                       // L1
  mlp_first(&X[0][0], 168, w_in_t, vb_in, &Hb[0][0], 136, lane, ftBase);  // L0
  WReg wB = wload(vw2_t, vb2, lane, ftBase);                       // L2
  mlp_c<0, 4>(&Hb[0][0], 136, wA, nullptr, 0, &X[0][0], 168, nullptr,
              lane, ftBase);                                        // L1
  wA = wload(vw1_t + 16384, vb1 + 128, lane, ftBase);              // L3
  mlp_c<1, 4>(&X[0][0], 168, wB, &Hb[0][0], 136, &Hb[0][0], 136, nullptr,
              lane, ftBase);                                        // L2
  wB = wload(vw2_t + 16384, vb2 + 128, lane, ftBase);              // L4
  mlp_c<0, 4>(&Hb[0][0], 136, wA, nullptr, 0, &X[0][0], 168, nullptr,
              lane, ftBase);                                        // L3
  wA = wload(vw1_t + 32768, vb1 + 256, lane, ftBase);              // L5
  mlp_c<1, 4>(&X[0][0], 168, wB, &Hb[0][0], 136, &Hb[0][0], 136, nullptr,
              lane, ftBase);                                        // L4
  wB = wload(vw2_t + 32768, vb2 + 256, lane, ftBase);              // L6
  mlp_c<0, 4>(&Hb[0][0], 136, wA, nullptr, 0, &X[0][0], 168, nullptr,
              lane, ftBase);                                        // L5
  wA = wload(vw_out_t, vb_out, lane, ftBase);                      // L7
  mlp_c<1, 4>(&X[0][0], 168, wB, &Hb[0][0], 136, &Hb[0][0], 136, nullptr,
              lane, ftBase);                                        // L6
  wB = wload(gw_in_t, gb_in, lane, ftBase);                        // G0
  mlp_c<2, 4>(&Hb[0][0], 136, wA, nullptr, 0, nullptr, 0, racc,
              lane, ftBase);                                        // L7 acc

  // mean over views -> X rows 0..15 cols 0..127
#pragma unroll
  for (int ftl = 0; ftl < 2; ++ftl) {
    u16x4 o;
#pragma unroll
    for (int r = 0; r < 4; ++r)
      o[r] = f2b(racc[ftl * 4 + r] * 0.25f);
    *(u16x4*)(&X[col][(ftBase + ftl) * 16 + quad * 4]) = o;
  }
  __syncthreads();

  wA = wload(gw1_t, gb1, lane, ftBase);                            // G1
  mlp_c<0, 1>(&X[0][0], 168, wB, nullptr, 0, &Hb[0][0], 136, nullptr,
              lane, ftBase);                                        // G0
  wB = wload(gw2_t, gb2, lane, ftBase);                            // G2
  mlp_c<0, 1>(&Hb[0][0], 136, wA, nullptr, 0, &X[0][0], 168, nullptr,
              lane, ftBase);                                        // G1
  wA = wload(gw1_t + 16384, gb1 + 128, lane, ftBase);              // G3
  mlp_c<1, 1>(&X[0][0], 168, wB, &Hb[0][0], 136, &Hb[0][0], 136, nullptr,
              lane, ftBase);                                        // G2
  wB = wload(gw2_t + 16384, gb2 + 128, lane, ftBase);              // G4
  mlp_c<0, 1>(&Hb[0][0], 136, wA, nullptr, 0, &X[0][0], 168, nullptr,
              lane, ftBase);                                        // G3
  mlp_c<1, 1>(&X[0][0], 168, wB, &Hb[0][0], 136, &Hb[0][0], 136, nullptr,
              lane, ftBase);                                        // G4

  // out = h @ gw_out + gb_out; 16 points, 4 lanes/point (wave 0)
  if (tid < 64) {
    const int p = tid & 15, q4 = tid >> 4;
    float s = 0.f;
    const unsigned short* hr = &Hb[p][q4 * 32];
    const float* wo = gw_out + q4 * 32;
#pragma unroll
    for (int c = 0; c < 32; ++c)
      s += b2f(hr[c]) * wo[c];
    s += __shfl_xor(s, 16, 64);
    s += __shfl_xor(s, 32, 64);
    if (q4 == 0)
      out[(size_t)b * NPTSC + pts0 + p] = s + gb_out[0];
  }
}

extern "C" void kernel_launch(void* const* d_in, const int* in_sizes, int n_in,
                              void* d_out, int out_size, void* d_ws, size_t ws_size,
                              hipStream_t stream) {
  const float* views  = (const float*)d_in[0];
  const float* angles = (const float*)d_in[1];
  const int*   idx    = (const int*)d_in[2];
  const float* conv_w = (const float*)d_in[3];
  const float* conv_b = (const float*)d_in[4];
  const float* vw_in  = (const float*)d_in[5];
  const float* vb_in  = (const float*)d_in[6];
  const float* vw1    = (const float*)d_in[7];
  const float* vb1    = (const float*)d_in[8];
  const float* vw2    = (const float*)d_in[9];
  const float* vb2    = (const float*)d_in[10];
  const float* vw_out = (const float*)d_in[11];
  const float* vb_out = (const float*)d_in[12];
  const float* gw_in  = (const float*)d_in[13];
  const float* gb_in  = (const float*)d_in[14];
  const float* gw1    = (const float*)d_in[15];
  const float* gb1    = (const float*)d_in[16];
  const float* gw2    = (const float*)d_in[17];
  const float* gb2    = (const float*)d_in[18];
  const float* gw_out = (const float*)d_in[19];
  const float* gb_out = (const float*)d_in[20];

  unsigned short* wbuf = (unsigned short*)d_ws;  // 434 KB

  hipLaunchKernelGGL(mvct_prep, dim3(848), dim3(256), 0, stream,
                     vw_in, vw1, vw2, vw_out, gw_in, gw1, gw2, wbuf);
  hipLaunchKernelGGL(mvct_conv, dim3(BB * VV * HH), dim3(128), 0, stream,
                     views, conv_w, conv_b);
  hipLaunchKernelGGL(mvct_main, dim3(BB * (NPTSC / 16)), dim3(256), 0, stream,
                     angles, idx, wbuf, vb_in, vb1, vb2, vb_out,
                     gb_in, gb1, gb2, gw_out, gb_out,
                     (float*)d_out);
}

// Round 28
// 530.411 us; speedup vs baseline: 2.2875x; 1.0174x over previous
//
#include <hip/hip_runtime.h>
#include <math.h>

#define BB 2
#define VV 4
#define NPTSC 65536
#define HH 256
#define WW 256
#define CCH 128

typedef __attribute__((ext_vector_type(8))) unsigned short ushort8;
typedef __attribute__((ext_vector_type(4))) unsigned short u16x4;
typedef __attribute__((ext_vector_type(8))) __bf16 bf16x8;
typedef __attribute__((ext_vector_type(4))) float floatx4;

// Static feats buffer (128 MiB); rewritten fully every launch.
__device__ unsigned short g_feats[(size_t)BB * VV * HH * WW * CCH];

__device__ __forceinline__ float b2f(unsigned short u) {
  unsigned int x = ((unsigned int)u) << 16;
  return __builtin_bit_cast(float, x);
}
__device__ __forceinline__ unsigned short f2b(float f) {
  unsigned int x = __builtin_bit_cast(unsigned int, f);
  x = x + 0x7fffu + ((x >> 16) & 1u);
  return (unsigned short)(x >> 16);
}

// ---- fused prep+conv ---------------------------------------------------------
// blocks 0..1023: conv, 2 y-rows per block (tid>>7 selects row half).
// blocks 1024..1871: prep (f32 weights -> bf16 [out][in] into d_ws, 434 KB).
__global__ __launch_bounds__(256) void mvct_pc(
    const float* __restrict__ views, const float* __restrict__ conv_w,
    const float* __restrict__ conv_b,
    const float* __restrict__ vw_in, const float* __restrict__ vw1,
    const float* __restrict__ vw2, const float* __restrict__ vw_out,
    const float* __restrict__ gw_in, const float* __restrict__ gw1,
    const float* __restrict__ gw2, unsigned short* __restrict__ wbuf)
{
  if (blockIdx.x < 1024) {
    // ---- conv 3x3 SAME, 1->128 ch, relu, channel-last bf16 ----
    __shared__ float rows[2][3][258];
    const int half = threadIdx.x >> 7;       // 0/1: which y row
    const int c = threadIdx.x & 127;         // out channel
    const int bv = blockIdx.x >> 7;          // 8 bv x 128 blocks
    const int y = ((blockIdx.x & 127) << 1) | half;

    float w[9];
#pragma unroll
    for (int j = 0; j < 9; ++j) w[j] = conv_w[c * 9 + j];
    float bias = conv_b[c];

    const float* img = views + (size_t)bv * HH * WW;
#pragma unroll
    for (int r = 0; r < 3; ++r) {
      int yy = y - 1 + r;
      for (int x = c; x < 258; x += 128) {
        int xx = x - 1;
        float v = 0.f;
        if (yy >= 0 && yy < HH && xx >= 0 && xx < WW) v = img[yy * WW + xx];
        rows[half][r][x] = v;
      }
    }
    __syncthreads();

    unsigned short* orow = g_feats + ((size_t)(bv * HH + y) * WW) * CCH + c;
    for (int x = 0; x < WW; ++x) {
      float acc = bias;
#pragma unroll
      for (int r = 0; r < 3; ++r)
#pragma unroll
        for (int d = 0; d < 3; ++d)
          acc += rows[half][r][x + d] * w[r * 3 + d];
      acc = fmaxf(acc, 0.f);
      orow[(size_t)x * CCH] = f2b(acc);
    }
  } else {
    // ---- prep ----
    int tid = (blockIdx.x - 1024) * 256 + threadIdx.x;
    if (tid >= 217088) return;
    float val;
    if (tid < 20480) {
      int n = tid / 160, k = tid - n * 160;
      val = (k < 137) ? vw_in[k * 128 + n] : 0.f;
    } else {
      int t = tid - 20480;
      const float* src;
      if (t < 49152) { src = vw1; }
      else if (t < 98304) { t -= 49152; src = vw2; }
      else if (t < 114688) { t -= 98304; src = vw_out; }
      else if (t < 131072) { t -= 114688; src = gw_in; }
      else if (t < 163840) { t -= 131072; src = gw1; }
      else { t -= 163840; src = gw2; }
      int i = t >> 14; int r = t & 16383; int n = r >> 7; int k = r & 127;
      val = src[i * 16384 + k * 128 + n];
    }
    wbuf[tid] = f2b(val);
  }
}

// ---- weight register set: 2 ftiles x 4 k-chunks (K=128) + biases -----------
struct WReg {
  ushort8 a[2][4];
  floatx4 bs[2];
};

__device__ __forceinline__ WReg wload(const unsigned short* __restrict__ Wt,
                                      const float* __restrict__ bias,
                                      int lane, int ftBase) {
  WReg w;
  const int col = lane & 15, quad = lane >> 4;
#pragma unroll
  for (int ftl = 0; ftl < 2; ++ftl) {
    const int ft = ftBase + ftl;
#pragma unroll
    for (int kk = 0; kk < 4; ++kk)
      w.a[ftl][kk] = *(const ushort8*)(Wt + (ft * 16 + col) * 128 + kk * 32 + quad * 8);
    w.bs[ftl] = *(const floatx4*)(bias + ft * 16 + quad * 4);
  }
  return w;
}

// ---- MFMA MLP compute (K=128), weights in registers ------------------------
// A=weights (m=out-feat), B=acts (n=row). D[m=ft*16+quad*4+r][n=ptt*16+col].
// MODE 0: relu+store; MODE 1: relu+residual+store; MODE 2: accumulate racc.
template<int MODE, int NPT>
__device__ __forceinline__ void mlp_c(
    const unsigned short* Act, int lda, const WReg& w,
    const unsigned short* Res, int ldr,
    unsigned short* Dst, int ldd,
    float* racc, int lane, int ftBase)
{
  const int col = lane & 15, quad = lane >> 4;
#pragma unroll
  for (int ptt = 0; ptt < NPT; ++ptt) {
    ushort8 bfr[4];
#pragma unroll
    for (int kk = 0; kk < 4; ++kk)
      bfr[kk] = *(const ushort8*)(Act + (ptt * 16 + col) * lda + kk * 32 + quad * 8);
#pragma unroll
    for (int ftl = 0; ftl < 2; ++ftl) {
      const int ft = ftBase + ftl;
      floatx4 acc = {0.f, 0.f, 0.f, 0.f};
#pragma unroll
      for (int kk = 0; kk < 4; ++kk)
        acc = __builtin_amdgcn_mfma_f32_16x16x32_bf16(
            __builtin_bit_cast(bf16x8, w.a[ftl][kk]),
            __builtin_bit_cast(bf16x8, bfr[kk]), acc, 0, 0, 0);
      const int row = ptt * 16 + col;
      if constexpr (MODE == 2) {
#pragma unroll
        for (int r = 0; r < 4; ++r)
          racc[ftl * 4 + r] += acc[r] + w.bs[ftl][r];
      } else {
        u16x4 rv;
        if constexpr (MODE == 1)
          rv = *(const u16x4*)(Res + row * ldr + ft * 16 + quad * 4);
        u16x4 o;
#pragma unroll
        for (int r = 0; r < 4; ++r) {
          float v = acc[r] + w.bs[ftl][r];
          if constexpr (MODE == 1) v += b2f(rv[r]);
          v = fmaxf(v, 0.f);
          o[r] = f2b(v);
        }
        *(u16x4*)(Dst + row * ldd + ft * 16 + quad * 4) = o;
      }
    }
  }
  __syncthreads();
}

// ---- first layer (K=160), self-loading weights -----------------------------
__device__ __forceinline__ void mlp_first(
    const unsigned short* Act, int lda,
    const unsigned short* __restrict__ Wt, const float* __restrict__ bias,
    unsigned short* Dst, int ldd, int lane, int ftBase)
{
  const int col = lane & 15, quad = lane >> 4;
  ushort8 afr[2][5];
  floatx4 bs4[2];
#pragma unroll
  for (int ftl = 0; ftl < 2; ++ftl) {
    const int ft = ftBase + ftl;
#pragma unroll
    for (int kk = 0; kk < 5; ++kk)
      afr[ftl][kk] = *(const ushort8*)(Wt + (ft * 16 + col) * 160 + kk * 32 + quad * 8);
    bs4[ftl] = *(const floatx4*)(bias + ft * 16 + quad * 4);
  }
#pragma unroll
  for (int ptt = 0; ptt < 4; ++ptt) {
    ushort8 bfr[5];
#pragma unroll
    for (int kk = 0; kk < 5; ++kk)
      bfr[kk] = *(const ushort8*)(Act + (ptt * 16 + col) * lda + kk * 32 + quad * 8);
#pragma unroll
    for (int ftl = 0; ftl < 2; ++ftl) {
      const int ft = ftBase + ftl;
      floatx4 acc = {0.f, 0.f, 0.f, 0.f};
#pragma unroll
      for (int kk = 0; kk < 5; ++kk)
        acc = __builtin_amdgcn_mfma_f32_16x16x32_bf16(
            __builtin_bit_cast(bf16x8, afr[ftl][kk]),
            __builtin_bit_cast(bf16x8, bfr[kk]), acc, 0, 0, 0);
      const int row = ptt * 16 + col;
      u16x4 o;
#pragma unroll
      for (int r = 0; r < 4; ++r)
        o[r] = f2b(fmaxf(acc[r] + bs4[ftl][r], 0.f));
      *(u16x4*)(Dst + row * ldd + ft * 16 + quad * 4) = o;
    }
  }
  __syncthreads();
}

// ---- main: 4-view-batched + explicit weight-prefetch pipeline --------------
// 8192 blocks x 256 thr (4 waves), 16 pts/block; rows = (view,point), 64 rows.
// (256,3): best verified config — tighter bounds spill (R25/R26), looser idles.
__global__ __launch_bounds__(256, 3) void mvct_main(
    const float* __restrict__ angles, const int* __restrict__ idx,
    const unsigned short* __restrict__ wbuf,
    const float* __restrict__ vb_in, const float* __restrict__ vb1,
    const float* __restrict__ vb2, const float* __restrict__ vb_out,
    const float* __restrict__ gb_in, const float* __restrict__ gb1,
    const float* __restrict__ gb2, const float* __restrict__ gw_out,
    const float* __restrict__ gb_out,
    float* __restrict__ out)
{
  __shared__ __align__(16) unsigned short X[64][168];
  __shared__ __align__(16) unsigned short Hb[64][136];
  const int tid = threadIdx.x;
  const int lane = tid & 63;
  const int ftBase = (tid >> 6) * 2;           // wave w: ftiles 2w, 2w+1
  const int b = blockIdx.x >> 12;              // 4096 groups per batch
  const int pts0 = (blockIdx.x & 4095) * 16;

  const unsigned short* w_in_t   = wbuf;
  const unsigned short* vw1_t    = wbuf + 20480;
  const unsigned short* vw2_t    = wbuf + 69632;
  const unsigned short* vw_out_t = wbuf + 118784;
  const unsigned short* gw_in_t  = wbuf + 135168;
  const unsigned short* gw1_t    = wbuf + 151552;
  const unsigned short* gw2_t    = wbuf + 184320;

  const float inv = 2.0f / 127.0f;
  const int col = lane & 15, quad = lane >> 4;

  // PE into X rows 0..63 cols 128..159 (per-row point p = row&15)
  if (tid < 64) {
    int p = tid & 15;
    int id = idx[pts0 + p];
    int iz = (id >> 14) & 127, iy = (id >> 7) & 127, ix = id & 127;
    float x = ix * inv - 1.f, y = iy * inv - 1.f, z = iz * inv - 1.f;
    const float PI = 3.14159265358979323846f;
    float pe[9] = {z, y, x, sinf(PI * z), sinf(PI * y), sinf(PI * x),
                   cosf(PI * z), cosf(PI * y), cosf(PI * x)};
#pragma unroll
    for (int j = 0; j < 9; ++j) X[tid][128 + j] = f2b(pe[j]);
    for (int j = 137; j < 160; ++j) X[tid][j] = 0;
  }

  // sampling: unrolled so the 4 views' independent gathers can overlap
#pragma unroll
  for (int v = 0; v < VV; ++v) {
    const int bv = b * VV + v;
    const float ang = angles[bv];
    const float ct = cosf(ang), st = sinf(ang);
    const int p = (tid >> 4) & 15, cg = tid & 15;
    int id = idx[pts0 + p];
    int iz = (id >> 14) & 127, iy = (id >> 7) & 127, ix = id & 127;
    float x = ix * inv - 1.f, y = iy * inv - 1.f, z = iz * inv - 1.f;
    float u = x * ct - y * st;
    float px = (u + 1.f) * 127.5f, py = (z + 1.f) * 127.5f;
    px = fminf(fmaxf(px, 0.f), 255.f);
    py = fminf(fmaxf(py, 0.f), 255.f);
    int x0 = min((int)px, 254), y0 = min((int)py, 254);
    float wx = px - (float)x0, wy = py - (float)y0;
    const unsigned short* bp =
        g_feats + ((size_t)((bv * HH + y0) * WW + x0)) * CCH + cg * 8;
    ushort8 q00 = *(const ushort8*)bp;
    ushort8 q01 = *(const ushort8*)(bp + CCH);
    ushort8 q10 = *(const ushort8*)(bp + WW * CCH);
    ushort8 q11 = *(const ushort8*)(bp + WW * CCH + CCH);
    float w00 = (1.f - wx) * (1.f - wy), w01 = wx * (1.f - wy);
    float w10 = (1.f - wx) * wy, w11 = wx * wy;
    ushort8 o;
#pragma unroll
    for (int j = 0; j < 8; ++j) {
      float f = w00 * b2f(q00[j]) + w01 * b2f(q01[j]) +
                w10 * b2f(q10[j]) + w11 * b2f(q11[j]);
      o[j] = f2b(f);
    }
    *(ushort8*)&X[v * 16 + p][cg * 8] = o;
  }
  __syncthreads();

  float racc[8];
#pragma unroll
  for (int i = 0; i < 8; ++i) racc[i] = 0.f;

  // Explicit software pipeline: wload(L+1) issues right after the previous
  // barrier and overlaps layer L's MFMA. By-value WReg, no pointers -> no spill.
  WReg wA = wload(vw1_t, vb1, lane, ftBase);                       // L1
  mlp_first(&X[0][0], 168, w_in_t, vb_in, &Hb[0][0], 136, lane, ftBase);  // L0
  WReg wB = wload(vw2_t, vb2, lane, ftBase);                       // L2
  mlp_c<0, 4>(&Hb[0][0], 136, wA, nullptr, 0, &X[0][0], 168, nullptr,
              lane, ftBase);                                        // L1
  wA = wload(vw1_t + 16384, vb1 + 128, lane, ftBase);              // L3
  mlp_c<1, 4>(&X[0][0], 168, wB, &Hb[0][0], 136, &Hb[0][0], 136, nullptr,
              lane, ftBase);                                        // L2
  wB = wload(vw2_t + 16384, vb2 + 128, lane, ftBase);              // L4
  mlp_c<0, 4>(&Hb[0][0], 136, wA, nullptr, 0, &X[0][0], 168, nullptr,
              lane, ftBase);                                        // L3
  wA = wload(vw1_t + 32768, vb1 + 256, lane, ftBase);              // L5
  mlp_c<1, 4>(&X[0][0], 168, wB, &Hb[0][0], 136, &Hb[0][0], 136, nullptr,
              lane, ftBase);                                        // L4
  wB = wload(vw2_t + 32768, vb2 + 256, lane, ftBase);              // L6
  mlp_c<0, 4>(&Hb[0][0], 136, wA, nullptr, 0, &X[0][0], 168, nullptr,
              lane, ftBase);                                        // L5
  wA = wload(vw_out_t, vb_out, lane, ftBase);                      // L7
  mlp_c<1, 4>(&X[0][0], 168, wB, &Hb[0][0], 136, &Hb[0][0], 136, nullptr,
              lane, ftBase);                                        // L6
  wB = wload(gw_in_t, gb_in, lane, ftBase);                        // G0
  mlp_c<2, 4>(&Hb[0][0], 136, wA, nullptr, 0, nullptr, 0, racc,
              lane, ftBase);                                        // L7 acc

  // mean over views -> X rows 0..15 cols 0..127
#pragma unroll
  for (int ftl = 0; ftl < 2; ++ftl) {
    u16x4 o;
#pragma unroll
    for (int r = 0; r < 4; ++r)
      o[r] = f2b(racc[ftl * 4 + r] * 0.25f);
    *(u16x4*)(&X[col][(ftBase + ftl) * 16 + quad * 4]) = o;
  }
  __syncthreads();

  wA = wload(gw1_t, gb1, lane, ftBase);                            // G1
  mlp_c<0, 1>(&X[0][0], 168, wB, nullptr, 0, &Hb[0][0], 136, nullptr,
              lane, ftBase);                                        // G0
  wB = wload(gw2_t, gb2, lane, ftBase);                            // G2
  mlp_c<0, 1>(&Hb[0][0], 136, wA, nullptr, 0, &X[0][0], 168, nullptr,
              lane, ftBase);                                        // G1
  wA = wload(gw1_t + 16384, gb1 + 128, lane, ftBase);              // G3
  mlp_c<1, 1>(&X[0][0], 168, wB, &Hb[0][0], 136, &Hb[0][0], 136, nullptr,
              lane, ftBase);                                        // G2
  wB = wload(gw2_t + 16384, gb2 + 128, lane, ftBase);              // G4
  mlp_c<0, 1>(&Hb[0][0], 136, wA, nullptr, 0, &X[0][0], 168, nullptr,
              lane, ftBase);                                        // G3
  mlp_c<1, 1>(&X[0][0], 168, wB, &Hb[0][0], 136, &Hb[0][0], 136, nullptr,
              lane, ftBase);                                        // G4

  // out = h @ gw_out + gb_out; 16 points, 4 lanes/point (wave 0)
  if (tid < 64) {
    const int p = tid & 15, q4 = tid >> 4;
    float s = 0.f;
    const unsigned short* hr = &Hb[p][q4 * 32];
    const float* wo = gw_out + q4 * 32;
#pragma unroll
    for (int c = 0; c < 32; ++c)
      s += b2f(hr[c]) * wo[c];
    s += __shfl_xor(s, 16, 64);
    s += __shfl_xor(s, 32, 64);
    if (q4 == 0)
      out[(size_t)b * NPTSC + pts0 + p] = s + gb_out[0];
  }
}

extern "C" void kernel_launch(void* const* d_in, const int* in_sizes, int n_in,
                              void* d_out, int out_size, void* d_ws, size_t ws_size,
                              hipStream_t stream) {
  const float* views  = (const float*)d_in[0];
  const float* angles = (const float*)d_in[1];
  const int*   idx    = (const int*)d_in[2];
  const float* conv_w = (const float*)d_in[3];
  const float* conv_b = (const float*)d_in[4];
  const float* vw_in  = (const float*)d_in[5];
  const float* vb_in  = (const float*)d_in[6];
  const float* vw1    = (const float*)d_in[7];
  const float* vb1    = (const float*)d_in[8];
  const float* vw2    = (const float*)d_in[9];
  const float* vb2    = (const float*)d_in[10];
  const float* vw_out = (const float*)d_in[11];
  const float* vb_out = (const float*)d_in[12];
  const float* gw_in  = (const float*)d_in[13];
  const float* gb_in  = (const float*)d_in[14];
  const float* gw1    = (const float*)d_in[15];
  const float* gb1    = (const float*)d_in[16];
  const float* gw2    = (const float*)d_in[17];
  const float* gb2    = (const float*)d_in[18];
  const float* gw_out = (const float*)d_in[19];
  const float* gb_out = (const float*)d_in[20];

  unsigned short* wbuf = (unsigned short*)d_ws;  // 434 KB

  // fused prep+conv: 1024 conv blocks + 848 prep blocks
  hipLaunchKernelGGL(mvct_pc, dim3(1872), dim3(256), 0, stream,
                     views, conv_w, conv_b,
                     vw_in, vw1, vw2, vw_out, gw_in, gw1, gw2, wbuf);
  hipLaunchKernelGGL(mvct_main, dim3(BB * (NPTSC / 16)), dim3(256), 0, stream,
                     angles, idx, wbuf, vb_in, vb1, vb2, vb_out,
                     gb_in, gb1, gb2, gw_out, gb_out,
                     (float*)d_out);
}